// Round 3
// baseline (631.729 us; speedup 1.0000x reference)
//
#include <hip/hip_runtime.h>

#define IN_DIM 128
#define HID 64
#define BKT 64            // nodes per bucket
#define NBMAX 1024        // max buckets (N <= 65536)

// Detect whether edge_index is int64 (odd int32 words of first 256 all zero) or int32.
__global__ void detect_kernel(const int* ei, int* flag) {
    int t = threadIdx.x;                       // 64 threads
    int nz = (ei[2 * t + 1] != 0) | (ei[2 * (t + 64) + 1] != 0);
    unsigned long long b = __ballot(nz);
    if (t == 0) *flag = (b == 0ULL) ? 1 : 0;
}

// Convert edge_index (either width) to int32 array of 2E entries, and histogram dst.
__global__ void convert_hist_kernel(const void* ei, const int* __restrict__ flag,
                                    int* __restrict__ out, int* cnt, int E) {
    int i = blockIdx.x * blockDim.x + threadIdx.x;
    int n2 = 2 * E;
    if (i < n2) {
        int v = (*flag) ? (int)((const long long*)ei)[i] : ((const int*)ei)[i];
        out[i] = v;
        if (i >= E) atomicAdd(&cnt[v], 1);  // dst half -> degree histogram
    }
}

// ---- hierarchical exclusive scan of cnt[N] -> off[N+1], plus dinv = rsqrt(cnt+1) ----

__global__ __launch_bounds__(256) void scanA_kernel(const int* __restrict__ cnt, int N,
                                                    int* __restrict__ bsum) {
    __shared__ int red[4];
    int i = blockIdx.x * 256 + threadIdx.x;
    int v = (i < N) ? cnt[i] : 0;
#pragma unroll
    for (int o = 32; o > 0; o >>= 1) v += __shfl_down(v, o, 64);
    int w = threadIdx.x >> 6, lane = threadIdx.x & 63;
    if (lane == 0) red[w] = v;
    __syncthreads();
    if (threadIdx.x == 0) bsum[blockIdx.x] = red[0] + red[1] + red[2] + red[3];
}

__global__ __launch_bounds__(1024) void scanB_kernel(const int* __restrict__ bsum, int nb,
                                                     int* __restrict__ boff, int* __restrict__ off, int N) {
    __shared__ int ls[1024];
    int t = threadIdx.x;
    int v = (t < nb) ? bsum[t] : 0;
    ls[t] = v;
    __syncthreads();
    for (int st = 1; st < 1024; st <<= 1) {
        int a = (t >= st) ? ls[t - st] : 0;
        __syncthreads();
        ls[t] += a;
        __syncthreads();
    }
    if (t < nb) boff[t] = ls[t] - v;   // exclusive
    if (t == 1023) off[N] = ls[1023];  // total == E
}

// Phase C: local scan + block offset; dinv; also init per-bucket cursors bcur[b]=off[64b].
__global__ __launch_bounds__(256) void scanC_kernel(const int* __restrict__ cnt, int N,
                                                    const int* __restrict__ boff,
                                                    int* __restrict__ off, float* __restrict__ dinv,
                                                    int* __restrict__ bcur) {
    __shared__ int ls[256];
    int t = threadIdx.x;
    int i = blockIdx.x * 256 + t;
    int c = (i < N) ? cnt[i] : 0;
    ls[t] = c;
    __syncthreads();
    for (int st = 1; st < 256; st <<= 1) {
        int a = (t >= st) ? ls[t - st] : 0;
        __syncthreads();
        ls[t] += a;
        __syncthreads();
    }
    if (i < N) {
        int o = boff[blockIdx.x] + ls[t] - c;
        off[i] = o;
        dinv[i] = rsqrtf((float)(c + 1));
        if ((i & (BKT - 1)) == 0) bcur[i / BKT] = o;
    }
}

// Bin edges by 64-node dst bucket. Entry = (src << 6) | (dst & 63).
// Per-block LDS histogram -> one global reservation per (block,bucket) -> direct write.
// Writes within a bucket from one block land consecutively -> L2 write-combined.
__global__ __launch_bounds__(256) void bin_kernel(const int* __restrict__ src, const int* __restrict__ dst,
                                                  int E, int NB, int* bcur, int* __restrict__ binned) {
    __shared__ int lhist[NBMAX];
    __shared__ int lbase[NBMAX];
    int t = threadIdx.x;
    int chunk = (E + gridDim.x - 1) / gridDim.x;
    int cs = blockIdx.x * chunk;
    int ce = cs + chunk; if (ce > E) ce = E;
#pragma unroll
    for (int b = t; b < NBMAX; b += 256) lhist[b] = 0;
    __syncthreads();
    for (int i = cs + t; i < ce; i += 256) atomicAdd(&lhist[dst[i] >> 6], 1);
    __syncthreads();
    for (int b = t; b < NB; b += 256) {
        int c = lhist[b];
        if (c) lbase[b] = atomicAdd(&bcur[b], c);
        lhist[b] = 0;  // reuse as local cursor
    }
    __syncthreads();
    for (int i = cs + t; i < ce; i += 256) {
        int d = dst[i];
        int b = d >> 6;
        int p = lbase[b] + atomicAdd(&lhist[b], 1);
        binned[p] = (src[i] << 6) | (d & 63);
    }
}

// g1 = dinv ⊙ (x @ W1).  Block: 32 rows x 64 cols; 256 threads, each 8 rows x 1 col.
__global__ __launch_bounds__(256) void gemm1_kernel(const float* __restrict__ x, const float* __restrict__ W1,
                                                    const float* __restrict__ dinv, float* __restrict__ g1, int N) {
    __shared__ float ws[IN_DIM * HID];   // 32 KB, layout [k][64]
    __shared__ float xs[32][IN_DIM];     // 16 KB
    int t = threadIdx.x;
    for (int i = t; i < IN_DIM * HID / 4; i += 256)
        ((float4*)ws)[i] = ((const float4*)W1)[i];
    int row0 = blockIdx.x * 32;
    for (int i = t; i < 32 * IN_DIM / 4; i += 256) {
        int r = i >> 5;
        int c4 = i & 31;
        float4 v = make_float4(0.f, 0.f, 0.f, 0.f);
        if (row0 + r < N) v = ((const float4*)x)[(size_t)(row0 + r) * (IN_DIM / 4) + c4];
        *(float4*)&xs[r][c4 * 4] = v;
    }
    __syncthreads();
    int tx = t & 63, ty = t >> 6;
    float acc[8] = {0.f, 0.f, 0.f, 0.f, 0.f, 0.f, 0.f, 0.f};
    const float4* xs4 = (const float4*)xs;
#pragma unroll 8
    for (int k4 = 0; k4 < 32; ++k4) {
        float w0 = ws[(4 * k4 + 0) * HID + tx];
        float w1 = ws[(4 * k4 + 1) * HID + tx];
        float w2 = ws[(4 * k4 + 2) * HID + tx];
        float w3 = ws[(4 * k4 + 3) * HID + tx];
#pragma unroll
        for (int j = 0; j < 8; ++j) {
            float4 xv = xs4[(ty + 4 * j) * 32 + k4];
            acc[j] = fmaf(xv.x, w0, acc[j]);
            acc[j] = fmaf(xv.y, w1, acc[j]);
            acc[j] = fmaf(xv.z, w2, acc[j]);
            acc[j] = fmaf(xv.w, w3, acc[j]);
        }
    }
#pragma unroll
    for (int j = 0; j < 8; ++j) {
        int r = row0 + ty + 4 * j;
        if (r < N) g1[(size_t)r * HID + tx] = dinv[r] * acc[j];
    }
}

// Layer-1 aggregation, block-per-bucket: LDS acc[64][64], lane = feature.
// Fused: + self loop, *dinv, +b1, relu, dot W2, *dinv -> g2.
__global__ __launch_bounds__(256) void gather1_kernel(const float* __restrict__ g1, const int* __restrict__ off,
                                                      const int* __restrict__ binned, const float* __restrict__ dinv,
                                                      const float* __restrict__ b1, const float* __restrict__ W2,
                                                      float* __restrict__ g2, int N) {
    __shared__ float acc[BKT][HID];      // 16 KB, row stride 64 floats -> 2 lanes/bank, free
    int t = threadIdx.x;
    int wid = t >> 6, lane = t & 63;
    int b = blockIdx.x;
    int v0 = b * BKT;
#pragma unroll
    for (int r = wid; r < BKT; r += 4) acc[r][lane] = 0.f;
    __syncthreads();
    int endn = v0 + BKT; if (endn > N) endn = N;
    int s = off[v0], e = off[endn];
    int i = s + 4 * wid;
    for (; i + 4 <= e; i += 16) {        // 4 waves x 4 edges in flight
        int a0 = binned[i], a1 = binned[i + 1], a2 = binned[i + 2], a3 = binned[i + 3];
        float f0 = g1[(size_t)(a0 >> 6) * HID + lane];
        float f1 = g1[(size_t)(a1 >> 6) * HID + lane];
        float f2 = g1[(size_t)(a2 >> 6) * HID + lane];
        float f3 = g1[(size_t)(a3 >> 6) * HID + lane];
        atomicAdd(&acc[a0 & 63][lane], f0);
        atomicAdd(&acc[a1 & 63][lane], f1);
        atomicAdd(&acc[a2 & 63][lane], f2);
        atomicAdd(&acc[a3 & 63][lane], f3);
    }
    for (; i < e; ++i) {                 // at most one wave tails <4 edges
        int a = binned[i];
        atomicAdd(&acc[a & 63][lane], g1[(size_t)(a >> 6) * HID + lane]);
    }
    __syncthreads();
    float bl = b1[lane], wl = W2[lane];
#pragma unroll
    for (int r = wid; r < BKT; r += 4) {
        int v = v0 + r;
        if (v >= N) break;
        float dv = dinv[v];
        float hpre = acc[r][lane] + g1[(size_t)v * HID + lane];   // + self loop
        float h = fmaxf(fmaf(dv, hpre, bl), 0.0f);
        float p = h * wl;
#pragma unroll
        for (int o = 32; o > 0; o >>= 1) p += __shfl_down(p, o, 64);
        if (lane == 0) g2[v] = dv * p;
    }
}

// Layer-2 aggregation on scalars, block-per-bucket.
__global__ __launch_bounds__(256) void gather2_kernel(const float* __restrict__ g2, const int* __restrict__ off,
                                                      const int* __restrict__ binned, const float* __restrict__ dinv,
                                                      const float* __restrict__ b2, float* __restrict__ out, int N) {
    __shared__ float sacc[BKT];
    int t = threadIdx.x;
    int b = blockIdx.x;
    int v0 = b * BKT;
    if (t < BKT) sacc[t] = 0.f;
    __syncthreads();
    int endn = v0 + BKT; if (endn > N) endn = N;
    int s = off[v0], e = off[endn];
    for (int i = s + t; i < e; i += 256) {
        int a = binned[i];
        atomicAdd(&sacc[a & 63], g2[a >> 6]);
    }
    __syncthreads();
    if (t < BKT) {
        int v = v0 + t;
        if (v < N) out[v] = fmaf(dinv[v], g2[v] + sacc[t], b2[0]);
    }
}

extern "C" void kernel_launch(void* const* d_in, const int* in_sizes, int n_in,
                              void* d_out, int out_size, void* d_ws, size_t ws_size,
                              hipStream_t stream) {
    const float* x  = (const float*)d_in[0];
    const void*  ei = d_in[1];
    const float* W1 = (const float*)d_in[2];
    const float* b1 = (const float*)d_in[3];
    const float* W2 = (const float*)d_in[4];
    const float* b2 = (const float*)d_in[5];
    float* out = (float*)d_out;

    int N = in_sizes[0] / IN_DIM;
    int E = in_sizes[1] / 2;
    int NB = (N + BKT - 1) / BKT;   // 782 for N=50000 (must be <= NBMAX)

    char* w = (char*)d_ws;
    size_t o = 0;
    auto alloc = [&](size_t bytes) { char* p = w + o; o = (o + bytes + 255) & ~(size_t)255; return p; };
    int*   flag   = (int*)  alloc(sizeof(int));
    int*   ei32   = (int*)  alloc((size_t)2 * E * sizeof(int));
    int*   off    = (int*)  alloc((size_t)(N + 1) * sizeof(int));
    int*   cnt    = (int*)  alloc((size_t)N * sizeof(int));
    float* dinv   = (float*)alloc((size_t)N * sizeof(float));
    int*   binned = (int*)  alloc((size_t)E * sizeof(int));
    float* g1     = (float*)alloc((size_t)N * HID * sizeof(float));
    float* g2     = (float*)alloc((size_t)N * sizeof(float));
    int*   bsum   = (int*)  alloc(1024 * sizeof(int));
    int*   boff   = (int*)  alloc(1024 * sizeof(int));
    int*   bcur   = (int*)  alloc((size_t)NBMAX * sizeof(int));
    (void)ws_size; (void)n_in; (void)out_size;

    const int tb = 256;
    int n2 = 2 * E;
    int nbs = (N + 255) / 256;  // <= 1024 for scanB

    detect_kernel<<<1, 64, 0, stream>>>((const int*)ei, flag);
    hipMemsetAsync(cnt, 0, (size_t)N * sizeof(int), stream);
    convert_hist_kernel<<<(n2 + tb - 1) / tb, tb, 0, stream>>>(ei, flag, ei32, cnt, E);
    const int* src = ei32;
    const int* dst = ei32 + E;

    scanA_kernel<<<nbs, 256, 0, stream>>>(cnt, N, bsum);
    scanB_kernel<<<1, 1024, 0, stream>>>(bsum, nbs, boff, off, N);
    scanC_kernel<<<nbs, 256, 0, stream>>>(cnt, N, boff, off, dinv, bcur);

    bin_kernel<<<256, 256, 0, stream>>>(src, dst, E, NB, bcur, binned);
    gemm1_kernel<<<(N + 31) / 32, 256, 0, stream>>>(x, W1, dinv, g1, N);
    gather1_kernel<<<NB, 256, 0, stream>>>(g1, off, binned, dinv, b1, W2, g2, N);
    gather2_kernel<<<NB, 256, 0, stream>>>(g2, off, binned, dinv, b2, out, N);
}

// Round 4
// 251.055 us; speedup vs baseline: 2.5163x; 2.5163x over previous
//
#include <hip/hip_runtime.h>

#define IN_DIM 128
#define HID 64
#define BKT 64            // nodes per bucket
#define NBMAX 1024        // max buckets (N <= 65536)

// Detect whether edge_index is int64 (odd int32 words of first 256 all zero) or int32.
__global__ void detect_kernel(const int* ei, int* flag) {
    int t = threadIdx.x;                       // 64 threads
    int nz = (ei[2 * t + 1] != 0) | (ei[2 * (t + 64) + 1] != 0);
    unsigned long long b = __ballot(nz);
    if (t == 0) *flag = (b == 0ULL) ? 1 : 0;
}

// Convert edge_index (either width) to int32 array of 2E entries, and histogram dst.
__global__ void convert_hist_kernel(const void* ei, const int* __restrict__ flag,
                                    int* __restrict__ out, int* cnt, int E) {
    int i = blockIdx.x * blockDim.x + threadIdx.x;
    int n2 = 2 * E;
    if (i < n2) {
        int v = (*flag) ? (int)((const long long*)ei)[i] : ((const int*)ei)[i];
        out[i] = v;
        if (i >= E) atomicAdd(&cnt[v], 1);  // dst half -> degree histogram
    }
}

// ---- hierarchical exclusive scan of cnt[N] -> off[N+1], plus dinv = rsqrt(cnt+1) ----

__global__ __launch_bounds__(256) void scanA_kernel(const int* __restrict__ cnt, int N,
                                                    int* __restrict__ bsum) {
    __shared__ int red[4];
    int i = blockIdx.x * 256 + threadIdx.x;
    int v = (i < N) ? cnt[i] : 0;
#pragma unroll
    for (int o = 32; o > 0; o >>= 1) v += __shfl_down(v, o, 64);
    int w = threadIdx.x >> 6, lane = threadIdx.x & 63;
    if (lane == 0) red[w] = v;
    __syncthreads();
    if (threadIdx.x == 0) bsum[blockIdx.x] = red[0] + red[1] + red[2] + red[3];
}

__global__ __launch_bounds__(1024) void scanB_kernel(const int* __restrict__ bsum, int nb,
                                                     int* __restrict__ boff, int* __restrict__ off, int N) {
    __shared__ int ls[1024];
    int t = threadIdx.x;
    int v = (t < nb) ? bsum[t] : 0;
    ls[t] = v;
    __syncthreads();
    for (int st = 1; st < 1024; st <<= 1) {
        int a = (t >= st) ? ls[t - st] : 0;
        __syncthreads();
        ls[t] += a;
        __syncthreads();
    }
    if (t < nb) boff[t] = ls[t] - v;   // exclusive
    if (t == 1023) off[N] = ls[1023];  // total == E
}

// Phase C: local scan + block offset; dinv; also init per-bucket cursors bcur[b]=off[64b].
__global__ __launch_bounds__(256) void scanC_kernel(const int* __restrict__ cnt, int N,
                                                    const int* __restrict__ boff,
                                                    int* __restrict__ off, float* __restrict__ dinv,
                                                    int* __restrict__ bcur) {
    __shared__ int ls[256];
    int t = threadIdx.x;
    int i = blockIdx.x * 256 + t;
    int c = (i < N) ? cnt[i] : 0;
    ls[t] = c;
    __syncthreads();
    for (int st = 1; st < 256; st <<= 1) {
        int a = (t >= st) ? ls[t - st] : 0;
        __syncthreads();
        ls[t] += a;
        __syncthreads();
    }
    if (i < N) {
        int o = boff[blockIdx.x] + ls[t] - c;
        off[i] = o;
        dinv[i] = rsqrtf((float)(c + 1));
        if ((i & (BKT - 1)) == 0) bcur[i / BKT] = o;
    }
}

// Bin edges by 64-node dst bucket. Entry = (src << 6) | (dst & 63).
// Per-block LDS histogram -> one global reservation per (block,bucket) -> direct write.
// Writes within a bucket from one block land consecutively -> L2 write-combined.
__global__ __launch_bounds__(256) void bin_kernel(const int* __restrict__ src, const int* __restrict__ dst,
                                                  int E, int NB, int* bcur, int* __restrict__ binned) {
    __shared__ int lhist[NBMAX];
    __shared__ int lbase[NBMAX];
    int t = threadIdx.x;
    int chunk = (E + gridDim.x - 1) / gridDim.x;
    int cs = blockIdx.x * chunk;
    int ce = cs + chunk; if (ce > E) ce = E;
    for (int b = t; b < NBMAX; b += 256) lhist[b] = 0;
    __syncthreads();
    for (int i = cs + t; i < ce; i += 256) atomicAdd(&lhist[dst[i] >> 6], 1);
    __syncthreads();
    for (int b = t; b < NB; b += 256) {
        int c = lhist[b];
        if (c) lbase[b] = atomicAdd(&bcur[b], c);
        lhist[b] = 0;  // reuse as local cursor
    }
    __syncthreads();
    for (int i = cs + t; i < ce; i += 256) {
        int d = dst[i];
        int b = d >> 6;
        int p = lbase[b] + atomicAdd(&lhist[b], 1);
        binned[p] = (src[i] << 6) | (d & 63);
    }
}

// Sort within bucket: block-per-bucket, LDS 64-counter histogram + wave scan + LDS cursors.
// Produces exact CSR (csr[p] = src, segment of node v = [off[v], off[v+1])).
// All global writes of a block land in one ~(bucket size * 4B) region -> write-combined.
__global__ __launch_bounds__(256) void sort_kernel(const int* __restrict__ binned,
                                                   const int* __restrict__ off, int N,
                                                   int* __restrict__ csr) {
    __shared__ int hist[BKT];
    __shared__ int cur[BKT];
    int t = threadIdx.x;
    int v0 = blockIdx.x * BKT;
    int endn = v0 + BKT; if (endn > N) endn = N;
    int s = off[v0], e = off[endn];
    if (t < BKT) hist[t] = 0;
    __syncthreads();
    for (int i = s + t; i < e; i += 256) atomicAdd(&hist[binned[i] & 63], 1);
    __syncthreads();
    if (t < 64) {                        // first wave: exclusive scan of 64 counters
        int c = hist[t];
        int sc = c;
#pragma unroll
        for (int o = 1; o < 64; o <<= 1) {
            int y = __shfl_up(sc, o, 64);
            if (t >= o) sc += y;
        }
        cur[t] = s + sc - c;             // global start of node v0+t's segment
    }
    __syncthreads();
    for (int i = s + t; i < e; i += 256) {
        int a = binned[i];
        int p = atomicAdd(&cur[a & 63], 1);
        csr[p] = a >> 6;
    }
}

// g1 = dinv ⊙ (x @ W1).  Block: 32 rows x 64 cols; 256 threads, each 8 rows x 1 col.
__global__ __launch_bounds__(256) void gemm1_kernel(const float* __restrict__ x, const float* __restrict__ W1,
                                                    const float* __restrict__ dinv, float* __restrict__ g1, int N) {
    __shared__ float ws[IN_DIM * HID];   // 32 KB, layout [k][64]
    __shared__ float xs[32][IN_DIM];     // 16 KB
    int t = threadIdx.x;
    for (int i = t; i < IN_DIM * HID / 4; i += 256)
        ((float4*)ws)[i] = ((const float4*)W1)[i];
    int row0 = blockIdx.x * 32;
    for (int i = t; i < 32 * IN_DIM / 4; i += 256) {
        int r = i >> 5;
        int c4 = i & 31;
        float4 v = make_float4(0.f, 0.f, 0.f, 0.f);
        if (row0 + r < N) v = ((const float4*)x)[(size_t)(row0 + r) * (IN_DIM / 4) + c4];
        *(float4*)&xs[r][c4 * 4] = v;
    }
    __syncthreads();
    int tx = t & 63, ty = t >> 6;
    float acc[8] = {0.f, 0.f, 0.f, 0.f, 0.f, 0.f, 0.f, 0.f};
    const float4* xs4 = (const float4*)xs;
#pragma unroll 8
    for (int k4 = 0; k4 < 32; ++k4) {
        float w0 = ws[(4 * k4 + 0) * HID + tx];
        float w1 = ws[(4 * k4 + 1) * HID + tx];
        float w2 = ws[(4 * k4 + 2) * HID + tx];
        float w3 = ws[(4 * k4 + 3) * HID + tx];
#pragma unroll
        for (int j = 0; j < 8; ++j) {
            float4 xv = xs4[(ty + 4 * j) * 32 + k4];
            acc[j] = fmaf(xv.x, w0, acc[j]);
            acc[j] = fmaf(xv.y, w1, acc[j]);
            acc[j] = fmaf(xv.z, w2, acc[j]);
            acc[j] = fmaf(xv.w, w3, acc[j]);
        }
    }
#pragma unroll
    for (int j = 0; j < 8; ++j) {
        int r = row0 + ty + 4 * j;
        if (r < N) g1[(size_t)r * HID + tx] = dinv[r] * acc[j];
    }
}

// Layer-1 aggregation (one wave per node, lane = feature) fused with
// relu + (h1 @ W2) wave-reduction -> g2[v] = dinv[v] * (relu(out1) @ W2)
// Register accumulation, no LDS -> max occupancy; 4 independent row loads in flight.
__global__ __launch_bounds__(256) void gather1_kernel(const float* __restrict__ g1, const int* __restrict__ off,
                                                      const int* __restrict__ csr, const float* __restrict__ dinv,
                                                      const float* __restrict__ b1, const float* __restrict__ W2,
                                                      float* __restrict__ g2, int N) {
    int wid = threadIdx.x >> 6;
    int lane = threadIdx.x & 63;
    int v = blockIdx.x * 4 + wid;
    if (v >= N) return;
    int s = off[v], e = off[v + 1];
    float acc = g1[(size_t)v * HID + lane];      // self loop
    int i = s;
    for (; i + 4 <= e; i += 4) {                 // 4 independent 256B row loads in flight
        int u0 = csr[i], u1 = csr[i + 1], u2 = csr[i + 2], u3 = csr[i + 3];
        float a0 = g1[(size_t)u0 * HID + lane];
        float a1 = g1[(size_t)u1 * HID + lane];
        float a2 = g1[(size_t)u2 * HID + lane];
        float a3 = g1[(size_t)u3 * HID + lane];
        acc += (a0 + a1) + (a2 + a3);
    }
    for (; i < e; ++i) acc += g1[(size_t)csr[i] * HID + lane];
    float dv = dinv[v];
    float h = fmaxf(fmaf(dv, acc, b1[lane]), 0.0f);   // out1 = dinv*acc + b1, relu
    float p = h * W2[lane];
#pragma unroll
    for (int o = 32; o > 0; o >>= 1) p += __shfl_down(p, o, 64);
    if (lane == 0) g2[v] = dv * p;
}

// Layer-2 aggregation on scalars: out[v] = dinv[v]*(g2[v] + sum g2[u]) + b2
__global__ __launch_bounds__(256) void gather2_kernel(const float* __restrict__ g2, const int* __restrict__ off,
                                                      const int* __restrict__ csr, const float* __restrict__ dinv,
                                                      const float* __restrict__ b2, float* __restrict__ out, int N) {
    int wid = threadIdx.x >> 6;
    int lane = threadIdx.x & 63;
    int v = blockIdx.x * 4 + wid;
    if (v >= N) return;
    int s = off[v], e = off[v + 1];
    float p = 0.f;
    for (int i = s + lane; i < e; i += 64) p += g2[csr[i]];
#pragma unroll
    for (int o = 32; o > 0; o >>= 1) p += __shfl_down(p, o, 64);
    if (lane == 0) out[v] = fmaf(dinv[v], g2[v] + p, b2[0]);
}

extern "C" void kernel_launch(void* const* d_in, const int* in_sizes, int n_in,
                              void* d_out, int out_size, void* d_ws, size_t ws_size,
                              hipStream_t stream) {
    const float* x  = (const float*)d_in[0];
    const void*  ei = d_in[1];
    const float* W1 = (const float*)d_in[2];
    const float* b1 = (const float*)d_in[3];
    const float* W2 = (const float*)d_in[4];
    const float* b2 = (const float*)d_in[5];
    float* out = (float*)d_out;

    int N = in_sizes[0] / IN_DIM;
    int E = in_sizes[1] / 2;
    int NB = (N + BKT - 1) / BKT;   // 782 for N=50000 (<= NBMAX)

    char* w = (char*)d_ws;
    size_t o = 0;
    auto alloc = [&](size_t bytes) { char* p = w + o; o = (o + bytes + 255) & ~(size_t)255; return p; };
    int*   flag   = (int*)  alloc(sizeof(int));
    int*   ei32   = (int*)  alloc((size_t)2 * E * sizeof(int));
    int*   off    = (int*)  alloc((size_t)(N + 1) * sizeof(int));
    int*   cnt    = (int*)  alloc((size_t)N * sizeof(int));
    float* dinv   = (float*)alloc((size_t)N * sizeof(float));
    int*   binned = (int*)  alloc((size_t)E * sizeof(int));
    int*   csr    = (int*)  alloc((size_t)E * sizeof(int));
    float* g1     = (float*)alloc((size_t)N * HID * sizeof(float));
    float* g2     = (float*)alloc((size_t)N * sizeof(float));
    int*   bsum   = (int*)  alloc(1024 * sizeof(int));
    int*   boff   = (int*)  alloc(1024 * sizeof(int));
    int*   bcur   = (int*)  alloc((size_t)NBMAX * sizeof(int));
    (void)ws_size; (void)n_in; (void)out_size;

    const int tb = 256;
    int n2 = 2 * E;
    int nbs = (N + 255) / 256;  // <= 1024 for scanB

    detect_kernel<<<1, 64, 0, stream>>>((const int*)ei, flag);
    hipMemsetAsync(cnt, 0, (size_t)N * sizeof(int), stream);
    convert_hist_kernel<<<(n2 + tb - 1) / tb, tb, 0, stream>>>(ei, flag, ei32, cnt, E);
    const int* src = ei32;
    const int* dst = ei32 + E;

    scanA_kernel<<<nbs, 256, 0, stream>>>(cnt, N, bsum);
    scanB_kernel<<<1, 1024, 0, stream>>>(bsum, nbs, boff, off, N);
    scanC_kernel<<<nbs, 256, 0, stream>>>(cnt, N, boff, off, dinv, bcur);

    bin_kernel<<<256, 256, 0, stream>>>(src, dst, E, NB, bcur, binned);
    sort_kernel<<<NB, 256, 0, stream>>>(binned, off, N, csr);
    gemm1_kernel<<<(N + 31) / 32, 256, 0, stream>>>(x, W1, dinv, g1, N);
    gather1_kernel<<<(N + 3) / 4, 256, 0, stream>>>(g1, off, csr, dinv, b1, W2, g2, N);
    gather2_kernel<<<(N + 3) / 4, 256, 0, stream>>>(g2, off, csr, dinv, b2, out, N);
}

// Round 5
// 196.956 us; speedup vs baseline: 3.2075x; 1.2747x over previous
//
#include <hip/hip_runtime.h>

#define IN_DIM 128
#define HID 64
#define BKT 64            // nodes per bucket
#define NBMAX 1024        // max buckets (N <= 65536)
#define SLACK 2048        // binned capacity per bucket (mean ~1279 for this graph, >20 sigma)

// Detect int64-vs-int32 edge_index (wave 0) and init per-bucket cursors bcur[b]=b*SLACK.
__global__ __launch_bounds__(1024) void detect_init_kernel(const int* ei, int* flag,
                                                           int* bcur, int NB) {
    int t = threadIdx.x;
    if (t < 64) {
        int nz = (ei[2 * t + 1] != 0) | (ei[2 * (t + 64) + 1] != 0);
        unsigned long long b = __ballot(nz);
        if (t == 0) *flag = (b == 0ULL) ? 1 : 0;
    }
    if (t < NB) bcur[t] = t * SLACK;
}

// Bin edges by 64-node dst bucket, converting from raw (int64|int32) edge_index on the fly.
// Entry = (src << 6) | (dst & 63). Per-block LDS histogram -> one global reservation per
// (block,bucket) -> direct writes; consecutive slots claimed by same block -> write-combined.
__global__ __launch_bounds__(256) void bin_kernel(const void* ei, const int* __restrict__ flag,
                                                  int E, int NB, int* bcur, int* __restrict__ binned) {
    __shared__ int lhist[NBMAX];
    __shared__ int lbase[NBMAX];
    int t = threadIdx.x;
    bool w64 = (*flag) != 0;
    int chunk = (E + gridDim.x - 1) / gridDim.x;
    int cs = blockIdx.x * chunk;
    int ce = cs + chunk; if (ce > E) ce = E;
    for (int b = t; b < NBMAX; b += 256) lhist[b] = 0;
    __syncthreads();
    for (int i = cs + t; i < ce; i += 256) {
        int d = w64 ? (int)((const long long*)ei)[E + i] : ((const int*)ei)[E + i];
        atomicAdd(&lhist[d >> 6], 1);
    }
    __syncthreads();
    for (int b = t; b < NB; b += 256) {
        int c = lhist[b];
        if (c) lbase[b] = atomicAdd(&bcur[b], c);
        lhist[b] = 0;  // reuse as local cursor
    }
    __syncthreads();
    for (int i = cs + t; i < ce; i += 256) {
        int s, d;
        if (w64) { s = (int)((const long long*)ei)[i]; d = (int)((const long long*)ei)[E + i]; }
        else     { s = ((const int*)ei)[i];            d = ((const int*)ei)[E + i]; }
        int b = d >> 6;
        int p = lbase[b] + atomicAdd(&lhist[b], 1);
        binned[p] = (s << 6) | (d & 63);
    }
}

// Single-block scan: bucket counts (bcur[b]-b*SLACK) -> exclusive bucket offsets boff[0..NB].
__global__ __launch_bounds__(1024) void bscan_kernel(const int* __restrict__ bcur, int NB, int E,
                                                     int* __restrict__ boff) {
    __shared__ int ls[1024];
    int t = threadIdx.x;
    int v = (t < NB) ? (bcur[t] - t * SLACK) : 0;
    ls[t] = v;
    __syncthreads();
    for (int st = 1; st < 1024; st <<= 1) {
        int a = (t >= st) ? ls[t - st] : 0;
        __syncthreads();
        ls[t] += a;
        __syncthreads();
    }
    if (t < NB) boff[t] = ls[t] - v;   // exclusive
    if (t == 0) boff[NB] = E;
}

// Sort within bucket (block-per-bucket): LDS 64-counter histogram + wave scan.
// Produces exact CSR (csr[p]=src), per-node off[v], and dinv[v]=rsqrt(deg+1).
// All global writes of a block land in one small region -> write-combined.
__global__ __launch_bounds__(256) void sort_kernel(const int* __restrict__ binned,
                                                   const int* __restrict__ bcur,
                                                   const int* __restrict__ boff, int N, int E,
                                                   int* __restrict__ off, float* __restrict__ dinv,
                                                   int* __restrict__ csr) {
    __shared__ int hist[BKT];
    __shared__ int cur[BKT];
    int t = threadIdx.x;
    int b = blockIdx.x;
    int v0 = b * BKT;
    int si = b * SLACK;          // binned segment [si, ei_)
    int ei_ = bcur[b];
    int base = boff[b];          // global CSR base of this bucket
    if (t < BKT) hist[t] = 0;
    __syncthreads();
    for (int i = si + t; i < ei_; i += 256) atomicAdd(&hist[binned[i] & 63], 1);
    __syncthreads();
    if (t < 64) {                // wave 0: exclusive scan of 64 counters
        int c = hist[t];
        int sc = c;
#pragma unroll
        for (int o = 1; o < 64; o <<= 1) {
            int y = __shfl_up(sc, o, 64);
            if (t >= o) sc += y;
        }
        int start = base + sc - c;
        cur[t] = start;
        int v = v0 + t;
        if (v < N) {
            off[v] = start;
            dinv[v] = rsqrtf((float)(c + 1));
        }
    }
    if (b == 0 && t == 64) off[N] = E;
    __syncthreads();
    for (int i = si + t; i < ei_; i += 256) {
        int a = binned[i];
        int p = atomicAdd(&cur[a & 63], 1);
        csr[p] = a >> 6;
    }
}

// g1 = dinv ⊙ (x @ W1).  Block: 32 rows x 64 cols; 256 threads, each 8 rows x 1 col.
__global__ __launch_bounds__(256) void gemm1_kernel(const float* __restrict__ x, const float* __restrict__ W1,
                                                    const float* __restrict__ dinv, float* __restrict__ g1, int N) {
    __shared__ float ws[IN_DIM * HID];   // 32 KB, layout [k][64]
    __shared__ float xs[32][IN_DIM];     // 16 KB
    int t = threadIdx.x;
    for (int i = t; i < IN_DIM * HID / 4; i += 256)
        ((float4*)ws)[i] = ((const float4*)W1)[i];
    int row0 = blockIdx.x * 32;
    for (int i = t; i < 32 * IN_DIM / 4; i += 256) {
        int r = i >> 5;
        int c4 = i & 31;
        float4 v = make_float4(0.f, 0.f, 0.f, 0.f);
        if (row0 + r < N) v = ((const float4*)x)[(size_t)(row0 + r) * (IN_DIM / 4) + c4];
        *(float4*)&xs[r][c4 * 4] = v;
    }
    __syncthreads();
    int tx = t & 63, ty = t >> 6;
    float acc[8] = {0.f, 0.f, 0.f, 0.f, 0.f, 0.f, 0.f, 0.f};
    const float4* xs4 = (const float4*)xs;
#pragma unroll 8
    for (int k4 = 0; k4 < 32; ++k4) {
        float w0 = ws[(4 * k4 + 0) * HID + tx];
        float w1 = ws[(4 * k4 + 1) * HID + tx];
        float w2 = ws[(4 * k4 + 2) * HID + tx];
        float w3 = ws[(4 * k4 + 3) * HID + tx];
#pragma unroll
        for (int j = 0; j < 8; ++j) {
            float4 xv = xs4[(ty + 4 * j) * 32 + k4];
            acc[j] = fmaf(xv.x, w0, acc[j]);
            acc[j] = fmaf(xv.y, w1, acc[j]);
            acc[j] = fmaf(xv.z, w2, acc[j]);
            acc[j] = fmaf(xv.w, w3, acc[j]);
        }
    }
#pragma unroll
    for (int j = 0; j < 8; ++j) {
        int r = row0 + ty + 4 * j;
        if (r < N) g1[(size_t)r * HID + tx] = dinv[r] * acc[j];
    }
}

// Layer-1 aggregation (one wave per node, lane = feature) fused with
// relu + (h1 @ W2) wave-reduction -> g2[v] = dinv[v] * (relu(out1) @ W2)
// Register accumulation, no LDS -> max occupancy; 4 independent row loads in flight.
__global__ __launch_bounds__(256) void gather1_kernel(const float* __restrict__ g1, const int* __restrict__ off,
                                                      const int* __restrict__ csr, const float* __restrict__ dinv,
                                                      const float* __restrict__ b1, const float* __restrict__ W2,
                                                      float* __restrict__ g2, int N) {
    int wid = threadIdx.x >> 6;
    int lane = threadIdx.x & 63;
    int v = blockIdx.x * 4 + wid;
    if (v >= N) return;
    int s = off[v], e = off[v + 1];
    float acc = g1[(size_t)v * HID + lane];      // self loop
    int i = s;
    for (; i + 4 <= e; i += 4) {                 // 4 independent 256B row loads in flight
        int u0 = csr[i], u1 = csr[i + 1], u2 = csr[i + 2], u3 = csr[i + 3];
        float a0 = g1[(size_t)u0 * HID + lane];
        float a1 = g1[(size_t)u1 * HID + lane];
        float a2 = g1[(size_t)u2 * HID + lane];
        float a3 = g1[(size_t)u3 * HID + lane];
        acc += (a0 + a1) + (a2 + a3);
    }
    for (; i < e; ++i) acc += g1[(size_t)csr[i] * HID + lane];
    float dv = dinv[v];
    float h = fmaxf(fmaf(dv, acc, b1[lane]), 0.0f);   // out1 = dinv*acc + b1, relu
    float p = h * W2[lane];
#pragma unroll
    for (int o = 32; o > 0; o >>= 1) p += __shfl_down(p, o, 64);
    if (lane == 0) g2[v] = dv * p;
}

// Layer-2 aggregation on scalars: out[v] = dinv[v]*(g2[v] + sum g2[u]) + b2
__global__ __launch_bounds__(256) void gather2_kernel(const float* __restrict__ g2, const int* __restrict__ off,
                                                      const int* __restrict__ csr, const float* __restrict__ dinv,
                                                      const float* __restrict__ b2, float* __restrict__ out, int N) {
    int wid = threadIdx.x >> 6;
    int lane = threadIdx.x & 63;
    int v = blockIdx.x * 4 + wid;
    if (v >= N) return;
    int s = off[v], e = off[v + 1];
    float p = 0.f;
    for (int i = s + lane; i < e; i += 64) p += g2[csr[i]];
#pragma unroll
    for (int o = 32; o > 0; o >>= 1) p += __shfl_down(p, o, 64);
    if (lane == 0) out[v] = fmaf(dinv[v], g2[v] + p, b2[0]);
}

extern "C" void kernel_launch(void* const* d_in, const int* in_sizes, int n_in,
                              void* d_out, int out_size, void* d_ws, size_t ws_size,
                              hipStream_t stream) {
    const float* x  = (const float*)d_in[0];
    const void*  ei = d_in[1];
    const float* W1 = (const float*)d_in[2];
    const float* b1 = (const float*)d_in[3];
    const float* W2 = (const float*)d_in[4];
    const float* b2 = (const float*)d_in[5];
    float* out = (float*)d_out;

    int N = in_sizes[0] / IN_DIM;
    int E = in_sizes[1] / 2;
    int NB = (N + BKT - 1) / BKT;   // 782 for N=50000 (<= NBMAX)

    char* w = (char*)d_ws;
    size_t o = 0;
    auto alloc = [&](size_t bytes) { char* p = w + o; o = (o + bytes + 255) & ~(size_t)255; return p; };
    int*   flag   = (int*)  alloc(sizeof(int));
    int*   bcur   = (int*)  alloc((size_t)NBMAX * sizeof(int));
    int*   boff   = (int*)  alloc((size_t)(NBMAX + 1) * sizeof(int));
    int*   off    = (int*)  alloc((size_t)(N + 1) * sizeof(int));
    float* dinv   = (float*)alloc((size_t)N * sizeof(float));
    int*   binned = (int*)  alloc((size_t)NB * SLACK * sizeof(int));
    int*   csr    = (int*)  alloc((size_t)E * sizeof(int));
    float* g1     = (float*)alloc((size_t)N * HID * sizeof(float));
    float* g2     = (float*)alloc((size_t)N * sizeof(float));
    (void)ws_size; (void)n_in; (void)out_size;

    detect_init_kernel<<<1, 1024, 0, stream>>>((const int*)ei, flag, bcur, NB);
    bin_kernel<<<256, 256, 0, stream>>>(ei, flag, E, NB, bcur, binned);
    bscan_kernel<<<1, 1024, 0, stream>>>(bcur, NB, E, boff);
    sort_kernel<<<NB, 256, 0, stream>>>(binned, bcur, boff, N, E, off, dinv, csr);
    gemm1_kernel<<<(N + 31) / 32, 256, 0, stream>>>(x, W1, dinv, g1, N);
    gather1_kernel<<<(N + 3) / 4, 256, 0, stream>>>(g1, off, csr, dinv, b1, W2, g2, N);
    gather2_kernel<<<(N + 3) / 4, 256, 0, stream>>>(g2, off, csr, dinv, b2, out, N);
}

// Round 6
// 184.304 us; speedup vs baseline: 3.4277x; 1.0687x over previous
//
#include <hip/hip_runtime.h>

#define IN_DIM 128
#define HID 64
#define BKT 64            // nodes per bucket
#define NBMAX 1024        // max buckets (N <= 65536)
#define SLACK 2048        // binned capacity per bucket (mean ~1279, >20 sigma)
#define BM 64             // gemm rows per block
#define BKK 64            // gemm k per phase

// Detect int64-vs-int32 edge_index (wave 0) and init per-bucket cursors bcur[b]=b*SLACK.
__global__ __launch_bounds__(1024) void detect_init_kernel(const int* ei, int* flag,
                                                           int* bcur, int NB) {
    int t = threadIdx.x;
    if (t < 64) {
        int nz = (ei[2 * t + 1] != 0) | (ei[2 * (t + 64) + 1] != 0);
        unsigned long long b = __ballot(nz);
        if (t == 0) *flag = (b == 0ULL) ? 1 : 0;
    }
    if (t < NB) bcur[t] = t * SLACK;
}

// Bin edges by 64-node dst bucket, converting from raw (int64|int32) edge_index on the fly.
// Entry = (src << 6) | (dst & 63). Per-block LDS histogram -> one global reservation per
// (block,bucket) -> direct writes; consecutive slots claimed by same block -> write-combined.
__global__ __launch_bounds__(256) void bin_kernel(const void* ei, const int* __restrict__ flag,
                                                  int E, int NB, int* bcur, int* __restrict__ binned) {
    __shared__ int lhist[NBMAX];
    __shared__ int lbase[NBMAX];
    int t = threadIdx.x;
    bool w64 = (*flag) != 0;
    int chunk = (E + gridDim.x - 1) / gridDim.x;
    int cs = blockIdx.x * chunk;
    int ce = cs + chunk; if (ce > E) ce = E;
    for (int b = t; b < NBMAX; b += 256) lhist[b] = 0;
    __syncthreads();
    for (int i = cs + t; i < ce; i += 256) {
        int d = w64 ? (int)((const long long*)ei)[E + i] : ((const int*)ei)[E + i];
        atomicAdd(&lhist[d >> 6], 1);
    }
    __syncthreads();
    for (int b = t; b < NB; b += 256) {
        int c = lhist[b];
        if (c) lbase[b] = atomicAdd(&bcur[b], c);
        lhist[b] = 0;  // reuse as local cursor
    }
    __syncthreads();
    for (int i = cs + t; i < ce; i += 256) {
        int s, d;
        if (w64) { s = (int)((const long long*)ei)[i]; d = (int)((const long long*)ei)[E + i]; }
        else     { s = ((const int*)ei)[i];            d = ((const int*)ei)[E + i]; }
        int b = d >> 6;
        int p = lbase[b] + atomicAdd(&lhist[b], 1);
        binned[p] = (s << 6) | (d & 63);
    }
}

// Single-block scan: bucket counts (bcur[b]-b*SLACK) -> exclusive bucket offsets boff[0..NB].
__global__ __launch_bounds__(1024) void bscan_kernel(const int* __restrict__ bcur, int NB, int E,
                                                     int* __restrict__ boff) {
    __shared__ int ls[1024];
    int t = threadIdx.x;
    int v = (t < NB) ? (bcur[t] - t * SLACK) : 0;
    ls[t] = v;
    __syncthreads();
    for (int st = 1; st < 1024; st <<= 1) {
        int a = (t >= st) ? ls[t - st] : 0;
        __syncthreads();
        ls[t] += a;
        __syncthreads();
    }
    if (t < NB) boff[t] = ls[t] - v;   // exclusive
    if (t == 0) boff[NB] = E;
}

// Sort within bucket (block-per-bucket): LDS 64-counter histogram + wave scan.
// Produces exact CSR (csr[p]=src), per-node off[v], and dinv[v]=rsqrt(deg+1).
__global__ __launch_bounds__(256) void sort_kernel(const int* __restrict__ binned,
                                                   const int* __restrict__ bcur,
                                                   const int* __restrict__ boff, int N, int E,
                                                   int* __restrict__ off, float* __restrict__ dinv,
                                                   int* __restrict__ csr) {
    __shared__ int hist[BKT];
    __shared__ int cur[BKT];
    int t = threadIdx.x;
    int b = blockIdx.x;
    int v0 = b * BKT;
    int si = b * SLACK;          // binned segment [si, ei_)
    int ei_ = bcur[b];
    int base = boff[b];          // global CSR base of this bucket
    if (t < BKT) hist[t] = 0;
    __syncthreads();
    for (int i = si + t; i < ei_; i += 256) atomicAdd(&hist[binned[i] & 63], 1);
    __syncthreads();
    if (t < 64) {                // wave 0: exclusive scan of 64 counters
        int c = hist[t];
        int sc = c;
#pragma unroll
        for (int o = 1; o < 64; o <<= 1) {
            int y = __shfl_up(sc, o, 64);
            if (t >= o) sc += y;
        }
        int start = base + sc - c;
        cur[t] = start;
        int v = v0 + t;
        if (v < N) {
            off[v] = start;
            dinv[v] = rsqrtf((float)(c + 1));
        }
    }
    if (b == 0 && t == 64) off[N] = E;
    __syncthreads();
    for (int i = si + t; i < ei_; i += 256) {
        int a = binned[i];
        int p = atomicAdd(&cur[a & 63], 1);
        csr[p] = a >> 6;
    }
}

// g1 = dinv ⊙ (x @ W1).  64x64 block, 256 threads, 4x4 register tile per thread.
// Rows/cols at stride 16 (r = ty+16rr, c = tx+16cc) + XOR-granule-swizzled LDS:
//  - xs granule (r,g) stored at r*16 + (g ^ (r&15)); read (r,k4) -> conflict-free
//    (within a wave: 4 distinct r -> 4 bank-groups, each 16-lane broadcast).
//  - ws (W^T) granule (c,g) at c*64/4... float addr c*64 + 4*(g ^ (c&15)) + e; read (c,k4):
//    16 distinct c (= tx) -> g'%8 spans 8 bank-groups -> 2-way (free).
// LDS traffic: 128 B per 64 FMA (2.25x less than previous 32-row version).
__global__ __launch_bounds__(256) void gemm1_kernel(const float* __restrict__ x, const float* __restrict__ W1,
                                                    const float* __restrict__ dinv, float* __restrict__ g1, int N) {
    __shared__ float xs[BM * BKK];   // 16 KB
    __shared__ float ws[HID * BKK];  // 16 KB
    int t = threadIdx.x;
    int tx = t & 15, ty = t >> 4;
    int row0 = blockIdx.x * BM;
    float acc[4][4] = {{0.f}};
    float4* xs4 = (float4*)xs;
    const float4* ws4c = (const float4*)ws;
#pragma unroll
    for (int ph = 0; ph < 2; ++ph) {
        int kb = ph * BKK;
        __syncthreads();           // protect previous phase's reads (no-op cost at ph=0)
        // stage x: 64 rows x 16 granules; id -> r = id>>4, g = id&15 (coalesced global read)
#pragma unroll
        for (int p = 0; p < 4; ++p) {
            int id = t + 256 * p;
            int r = id >> 4, g = id & 15;
            float4 v = make_float4(0.f, 0.f, 0.f, 0.f);
            int gr = row0 + r;
            if (gr < N) v = ((const float4*)x)[(size_t)gr * (IN_DIM / 4) + (kb >> 2) + g];
            xs4[r * 16 + (g ^ (r & 15))] = v;
        }
        // stage W^T: read W1[kb+k][4c..4c+3] coalesced, scatter 4 floats to swizzled ws
#pragma unroll
        for (int p = 0; p < 4; ++p) {
            int id = t + 256 * p;
            int k = id >> 4;                 // local k 0..63
            int c0 = (id & 15) * 4;
            float4 v = ((const float4*)W1)[(size_t)(kb + k) * (HID / 4) + (id & 15)];
            int g = k >> 2, e = k & 3;
            ws[(c0 + 0) * 64 + 4 * (g ^ ((c0 + 0) & 15)) + e] = v.x;
            ws[(c0 + 1) * 64 + 4 * (g ^ ((c0 + 1) & 15)) + e] = v.y;
            ws[(c0 + 2) * 64 + 4 * (g ^ ((c0 + 2) & 15)) + e] = v.z;
            ws[(c0 + 3) * 64 + 4 * (g ^ ((c0 + 3) & 15)) + e] = v.w;
        }
        __syncthreads();
#pragma unroll 4
        for (int k4 = 0; k4 < 16; ++k4) {
            float4 xr[4], wc[4];
#pragma unroll
            for (int rr = 0; rr < 4; ++rr) {
                int r = ty + 16 * rr;        // r&15 == ty
                xr[rr] = xs4[r * 16 + (k4 ^ ty)];
            }
#pragma unroll
            for (int cc = 0; cc < 4; ++cc) {
                int c = tx + 16 * cc;        // c&15 == tx
                wc[cc] = ws4c[c * 16 + (k4 ^ tx)];
            }
#pragma unroll
            for (int rr = 0; rr < 4; ++rr)
#pragma unroll
                for (int cc = 0; cc < 4; ++cc) {
                    acc[rr][cc] = fmaf(xr[rr].x, wc[cc].x, acc[rr][cc]);
                    acc[rr][cc] = fmaf(xr[rr].y, wc[cc].y, acc[rr][cc]);
                    acc[rr][cc] = fmaf(xr[rr].z, wc[cc].z, acc[rr][cc]);
                    acc[rr][cc] = fmaf(xr[rr].w, wc[cc].w, acc[rr][cc]);
                }
        }
    }
#pragma unroll
    for (int rr = 0; rr < 4; ++rr) {
        int r = row0 + ty + 16 * rr;
        if (r < N) {
            float dv = dinv[r];
#pragma unroll
            for (int cc = 0; cc < 4; ++cc)
                g1[(size_t)r * HID + tx + 16 * cc] = dv * acc[rr][cc];
        }
    }
}

// Layer-1 aggregation (one wave per node, lane = feature) fused with
// relu + (h1 @ W2) wave-reduction -> g2[v] = dinv[v] * (relu(out1) @ W2)
// int4 broadcast index loads (1 VMEM per 4 edges) + 8 row loads in flight.
__global__ __launch_bounds__(256) void gather1_kernel(const float* __restrict__ g1, const int* __restrict__ off,
                                                      const int* __restrict__ csr, const float* __restrict__ dinv,
                                                      const float* __restrict__ b1, const float* __restrict__ W2,
                                                      float* __restrict__ g2, int N) {
    int wid = threadIdx.x >> 6;
    int lane = threadIdx.x & 63;
    int v = blockIdx.x * 4 + wid;
    if (v >= N) return;
    int s = off[v], e = off[v + 1];
    float acc = g1[(size_t)v * HID + lane];      // self loop
    int i = s;
    while (i < e && (i & 3)) { acc += g1[(size_t)csr[i] * HID + lane]; ++i; }  // align to 16B
    for (; i + 8 <= e; i += 8) {                 // 8 independent 256B row loads in flight
        int4 a = *(const int4*)(csr + i);
        int4 b = *(const int4*)(csr + i + 4);
        float f0 = g1[(size_t)a.x * HID + lane];
        float f1 = g1[(size_t)a.y * HID + lane];
        float f2 = g1[(size_t)a.z * HID + lane];
        float f3 = g1[(size_t)a.w * HID + lane];
        float f4 = g1[(size_t)b.x * HID + lane];
        float f5 = g1[(size_t)b.y * HID + lane];
        float f6 = g1[(size_t)b.z * HID + lane];
        float f7 = g1[(size_t)b.w * HID + lane];
        acc += ((f0 + f1) + (f2 + f3)) + ((f4 + f5) + (f6 + f7));
    }
    if (i + 4 <= e) {
        int4 a = *(const int4*)(csr + i);
        float f0 = g1[(size_t)a.x * HID + lane];
        float f1 = g1[(size_t)a.y * HID + lane];
        float f2 = g1[(size_t)a.z * HID + lane];
        float f3 = g1[(size_t)a.w * HID + lane];
        acc += (f0 + f1) + (f2 + f3);
        i += 4;
    }
    for (; i < e; ++i) acc += g1[(size_t)csr[i] * HID + lane];
    float dv = dinv[v];
    float h = fmaxf(fmaf(dv, acc, b1[lane]), 0.0f);   // out1 = dinv*acc + b1, relu
    float p = h * W2[lane];
#pragma unroll
    for (int o = 32; o > 0; o >>= 1) p += __shfl_down(p, o, 64);
    if (lane == 0) g2[v] = dv * p;
}

// Layer-2 aggregation on scalars: out[v] = dinv[v]*(g2[v] + sum g2[u]) + b2
__global__ __launch_bounds__(256) void gather2_kernel(const float* __restrict__ g2, const int* __restrict__ off,
                                                      const int* __restrict__ csr, const float* __restrict__ dinv,
                                                      const float* __restrict__ b2, float* __restrict__ out, int N) {
    int wid = threadIdx.x >> 6;
    int lane = threadIdx.x & 63;
    int v = blockIdx.x * 4 + wid;
    if (v >= N) return;
    int s = off[v], e = off[v + 1];
    float p = 0.f;
    for (int i = s + lane; i < e; i += 64) p += g2[csr[i]];
#pragma unroll
    for (int o = 32; o > 0; o >>= 1) p += __shfl_down(p, o, 64);
    if (lane == 0) out[v] = fmaf(dinv[v], g2[v] + p, b2[0]);
}

extern "C" void kernel_launch(void* const* d_in, const int* in_sizes, int n_in,
                              void* d_out, int out_size, void* d_ws, size_t ws_size,
                              hipStream_t stream) {
    const float* x  = (const float*)d_in[0];
    const void*  ei = d_in[1];
    const float* W1 = (const float*)d_in[2];
    const float* b1 = (const float*)d_in[3];
    const float* W2 = (const float*)d_in[4];
    const float* b2 = (const float*)d_in[5];
    float* out = (float*)d_out;

    int N = in_sizes[0] / IN_DIM;
    int E = in_sizes[1] / 2;
    int NB = (N + BKT - 1) / BKT;   // 782 for N=50000 (<= NBMAX)

    char* w = (char*)d_ws;
    size_t o = 0;
    auto alloc = [&](size_t bytes) { char* p = w + o; o = (o + bytes + 255) & ~(size_t)255; return p; };
    int*   flag   = (int*)  alloc(sizeof(int));
    int*   bcur   = (int*)  alloc((size_t)NBMAX * sizeof(int));
    int*   boff   = (int*)  alloc((size_t)(NBMAX + 1) * sizeof(int));
    int*   off    = (int*)  alloc((size_t)(N + 1) * sizeof(int));
    float* dinv   = (float*)alloc((size_t)N * sizeof(float));
    int*   binned = (int*)  alloc((size_t)NB * SLACK * sizeof(int));
    int*   csr    = (int*)  alloc((size_t)E * sizeof(int));
    float* g1     = (float*)alloc((size_t)N * HID * sizeof(float));
    float* g2     = (float*)alloc((size_t)N * sizeof(float));
    (void)ws_size; (void)n_in; (void)out_size;

    detect_init_kernel<<<1, 1024, 0, stream>>>((const int*)ei, flag, bcur, NB);
    bin_kernel<<<256, 256, 0, stream>>>(ei, flag, E, NB, bcur, binned);
    bscan_kernel<<<1, 1024, 0, stream>>>(bcur, NB, E, boff);
    sort_kernel<<<NB, 256, 0, stream>>>(binned, bcur, boff, N, E, off, dinv, csr);
    gemm1_kernel<<<(N + BM - 1) / BM, 256, 0, stream>>>(x, W1, dinv, g1, N);
    gather1_kernel<<<(N + 3) / 4, 256, 0, stream>>>(g1, off, csr, dinv, b1, W2, g2, N);
    gather2_kernel<<<(N + 3) / 4, 256, 0, stream>>>(g2, off, csr, dinv, b2, out, N);
}

// Round 8
// 184.240 us; speedup vs baseline: 3.4288x; 1.0003x over previous
//
#include <hip/hip_runtime.h>

#define IN_DIM 128
#define HID 64
#define BKT 64            // nodes per bucket
#define NBMAX 1024        // max buckets (N <= 65536)
#define SLACK 2048        // binned capacity per bucket (mean ~1279, >20 sigma)
#define BM 64             // gemm rows per block
#define CHUNKMAX 4096     // bin: max edges cached per block (16 KB LDS)

// Bin edges by 64-node dst bucket, converting from raw (int64|int32) edge_index on the fly.
// int64-detect is done per-block (reads first 256 int32 words; odd words all zero => int64).
// Entry = (src << 6) | (dst & 63). Per-block LDS histogram -> one global reservation per
// (block,bucket) into zero-initialized bcnt -> direct writes at b*SLACK + base + local;
// consecutive slots claimed by same block -> L2 write-combined.
// Pass 1 caches converted dst in LDS so pass 2 only reads the src half.
__global__ __launch_bounds__(512) void bin_kernel(const void* ei, int E, int NB,
                                                  int* bcnt, int* __restrict__ binned) {
    __shared__ int lhist[NBMAX];
    __shared__ int lbase[NBMAX];
    __shared__ int dcache[CHUNKMAX];
    __shared__ int sflag;
    int t = threadIdx.x;
    if (t < 64) {
        const int* ei32 = (const int*)ei;
        int nz = (ei32[2 * t + 1] != 0) | (ei32[2 * (t + 64) + 1] != 0);
        unsigned long long bl = __ballot(nz);
        if (t == 0) sflag = (bl == 0ULL) ? 1 : 0;
    }
    for (int b = t; b < NBMAX; b += 512) lhist[b] = 0;
    __syncthreads();
    bool w64 = sflag != 0;
    int chunk = (E + gridDim.x - 1) / gridDim.x;
    int cs = blockIdx.x * chunk;
    int ce = cs + chunk; if (ce > E) ce = E;
    for (int i = cs + t; i < ce; i += 512) {
        int d = w64 ? (int)((const long long*)ei)[E + i] : ((const int*)ei)[E + i];
        int j = i - cs;
        if (j < CHUNKMAX) dcache[j] = d;
        atomicAdd(&lhist[d >> 6], 1);
    }
    __syncthreads();
    for (int b = t; b < NB; b += 512) {
        int c = lhist[b];
        if (c) lbase[b] = b * SLACK + atomicAdd(&bcnt[b], c);
        lhist[b] = 0;  // reuse as local cursor
    }
    __syncthreads();
    for (int i = cs + t; i < ce; i += 512) {
        int s = w64 ? (int)((const long long*)ei)[i] : ((const int*)ei)[i];
        int j = i - cs;
        int d = (j < CHUNKMAX) ? dcache[j]
                               : (w64 ? (int)((const long long*)ei)[E + i] : ((const int*)ei)[E + i]);
        int b = d >> 6;
        int p = lbase[b] + atomicAdd(&lhist[b], 1);
        binned[p] = (s << 6) | (d & 63);
    }
}

// Sort within bucket (block-per-bucket). Inline exclusive prefix over bcnt[0..b) (L2-hot)
// replaces the separate bscan kernel. LDS 64-counter histogram + wave scan produce exact
// CSR (csr[p]=src), per-node off[v], and dinv[v]=rsqrt(deg+1).
__global__ __launch_bounds__(256) void sort_kernel(const int* __restrict__ binned,
                                                   const int* __restrict__ bcnt, int N, int E,
                                                   int* __restrict__ off, float* __restrict__ dinv,
                                                   int* __restrict__ csr) {
    __shared__ int hist[BKT];
    __shared__ int cur[BKT];
    __shared__ int pred[4];
    int t = threadIdx.x;
    int b = blockIdx.x;
    int v0 = b * BKT;
    // inline prefix: base = sum_{j<b} bcnt[j]
    int part = 0;
    for (int j = t; j < b; j += 256) part += bcnt[j];
#pragma unroll
    for (int o = 32; o > 0; o >>= 1) part += __shfl_down(part, o, 64);
    if ((t & 63) == 0) pred[t >> 6] = part;
    if (t < BKT) hist[t] = 0;
    __syncthreads();
    int base = pred[0] + pred[1] + pred[2] + pred[3];
    int cnt_b = bcnt[b];                 // broadcast load
    int si = b * SLACK, ei_ = si + cnt_b;
    for (int i = si + t; i < ei_; i += 256) atomicAdd(&hist[binned[i] & 63], 1);
    __syncthreads();
    if (t < 64) {                        // wave 0: exclusive scan of 64 counters
        int c = hist[t];
        int sc = c;
#pragma unroll
        for (int o = 1; o < 64; o <<= 1) {
            int y = __shfl_up(sc, o, 64);
            if (t >= o) sc += y;
        }
        int start = base + sc - c;
        cur[t] = start;
        int v = v0 + t;
        if (v < N) {
            off[v] = start;
            dinv[v] = rsqrtf((float)(c + 1));
        }
    }
    if (b == 0 && t == 64) off[N] = E;
    __syncthreads();
    for (int i = si + t; i < ei_; i += 256) {
        int a = binned[i];
        int p = atomicAdd(&cur[a & 63], 1);
        csr[p] = a >> 6;
    }
}

// g1 = dinv ⊙ (x @ W1).  W-in-registers: each lane owns W column `lane` (128 VGPRs,
// statically indexed via fully-unrolled k-loop). x rows staged in LDS, read as
// wave-uniform b128 broadcasts (no bank traffic) -> 1 LDS read per 4 FMA -> FMA-bound.
__global__ __launch_bounds__(256) void gemm1_kernel(const float* __restrict__ x, const float* __restrict__ W1,
                                                    const float* __restrict__ dinv, float* __restrict__ g1, int N) {
    __shared__ float xs[BM * IN_DIM];    // 32 KB = 2048 float4
    int t = threadIdx.x;
    int lane = t & 63, wv = t >> 6;
    int row0 = blockIdx.x * BM;
    float wreg[IN_DIM];
#pragma unroll
    for (int k = 0; k < IN_DIM; ++k) wreg[k] = W1[k * HID + lane];   // coalesced 256B/instr
    // stage x: 64 rows x 32 float4 = 2048 float4 -> 8 passes of 256 threads
#pragma unroll
    for (int p = 0; p < 8; ++p) {
        int id = t + 256 * p;            // id = r*32 + g
        int r = id >> 5, g = id & 31;
        float4 v = make_float4(0.f, 0.f, 0.f, 0.f);
        int gr = row0 + r;
        if (gr < N) v = ((const float4*)x)[(size_t)gr * (IN_DIM / 4) + g];
        ((float4*)xs)[id] = v;
    }
    __syncthreads();
    const float4* xs4 = (const float4*)xs;
    for (int rr = 0; rr < 16; ++rr) {    // dynamic loop; acc is scalar -> all reg-static
        int r = wv * 16 + rr;
        float acc = 0.f;
#pragma unroll
        for (int k4 = 0; k4 < 32; ++k4) {
            float4 xv = xs4[r * 32 + k4];            // wave-uniform broadcast
            acc = fmaf(xv.x, wreg[4 * k4 + 0], acc);
            acc = fmaf(xv.y, wreg[4 * k4 + 1], acc);
            acc = fmaf(xv.z, wreg[4 * k4 + 2], acc);
            acc = fmaf(xv.w, wreg[4 * k4 + 3], acc);
        }
        int gr = row0 + r;
        if (gr < N) g1[(size_t)gr * HID + lane] = dinv[gr] * acc;    // coalesced 256B store
    }
}

// Layer-1 aggregation (one wave per node, lane = feature) fused with
// relu + (h1 @ W2) wave-reduction -> g2[v] = dinv[v] * (relu(out1) @ W2)
// int4 broadcast index loads + 8 independent 256B row loads in flight.
__global__ __launch_bounds__(256) void gather1_kernel(const float* __restrict__ g1, const int* __restrict__ off,
                                                      const int* __restrict__ csr, const float* __restrict__ dinv,
                                                      const float* __restrict__ b1, const float* __restrict__ W2,
                                                      float* __restrict__ g2, int N) {
    int wid = threadIdx.x >> 6;
    int lane = threadIdx.x & 63;
    int v = blockIdx.x * 4 + wid;
    if (v >= N) return;
    int s = off[v], e = off[v + 1];
    float acc = g1[(size_t)v * HID + lane];      // self loop
    int i = s;
    while (i < e && (i & 3)) { acc += g1[(size_t)csr[i] * HID + lane]; ++i; }  // align to 16B
    for (; i + 8 <= e; i += 8) {
        int4 a = *(const int4*)(csr + i);
        int4 b = *(const int4*)(csr + i + 4);
        float f0 = g1[(size_t)a.x * HID + lane];
        float f1 = g1[(size_t)a.y * HID + lane];
        float f2 = g1[(size_t)a.z * HID + lane];
        float f3 = g1[(size_t)a.w * HID + lane];
        float f4 = g1[(size_t)b.x * HID + lane];
        float f5 = g1[(size_t)b.y * HID + lane];
        float f6 = g1[(size_t)b.z * HID + lane];
        float f7 = g1[(size_t)b.w * HID + lane];
        acc += ((f0 + f1) + (f2 + f3)) + ((f4 + f5) + (f6 + f7));
    }
    if (i + 4 <= e) {
        int4 a = *(const int4*)(csr + i);
        float f0 = g1[(size_t)a.x * HID + lane];
        float f1 = g1[(size_t)a.y * HID + lane];
        float f2 = g1[(size_t)a.z * HID + lane];
        float f3 = g1[(size_t)a.w * HID + lane];
        acc += (f0 + f1) + (f2 + f3);
        i += 4;
    }
    for (; i < e; ++i) acc += g1[(size_t)csr[i] * HID + lane];
    float dv = dinv[v];
    float h = fmaxf(fmaf(dv, acc, b1[lane]), 0.0f);   // out1 = dinv*acc + b1, relu
    float p = h * W2[lane];
#pragma unroll
    for (int o = 32; o > 0; o >>= 1) p += __shfl_down(p, o, 64);
    if (lane == 0) g2[v] = dv * p;
}

// Layer-2 aggregation on scalars: out[v] = dinv[v]*(g2[v] + sum g2[u]) + b2
__global__ __launch_bounds__(256) void gather2_kernel(const float* __restrict__ g2, const int* __restrict__ off,
                                                      const int* __restrict__ csr, const float* __restrict__ dinv,
                                                      const float* __restrict__ b2, float* __restrict__ out, int N) {
    int wid = threadIdx.x >> 6;
    int lane = threadIdx.x & 63;
    int v = blockIdx.x * 4 + wid;
    if (v >= N) return;
    int s = off[v], e = off[v + 1];
    float p = 0.f;
    for (int i = s + lane; i < e; i += 64) p += g2[csr[i]];
#pragma unroll
    for (int o = 32; o > 0; o >>= 1) p += __shfl_down(p, o, 64);
    if (lane == 0) out[v] = fmaf(dinv[v], g2[v] + p, b2[0]);
}

extern "C" void kernel_launch(void* const* d_in, const int* in_sizes, int n_in,
                              void* d_out, int out_size, void* d_ws, size_t ws_size,
                              hipStream_t stream) {
    const float* x  = (const float*)d_in[0];
    const void*  ei = d_in[1];
    const float* W1 = (const float*)d_in[2];
    const float* b1 = (const float*)d_in[3];
    const float* W2 = (const float*)d_in[4];
    const float* b2 = (const float*)d_in[5];
    float* out = (float*)d_out;

    int N = in_sizes[0] / IN_DIM;
    int E = in_sizes[1] / 2;
    int NB = (N + BKT - 1) / BKT;   // 782 for N=50000 (<= NBMAX)

    char* w = (char*)d_ws;
    size_t o = 0;
    auto alloc = [&](size_t bytes) { char* p = w + o; o = (o + bytes + 255) & ~(size_t)255; return p; };
    int*   bcnt   = (int*)  alloc((size_t)NBMAX * sizeof(int));
    int*   off    = (int*)  alloc((size_t)(N + 1) * sizeof(int));
    float* dinv   = (float*)alloc((size_t)N * sizeof(float));
    int*   binned = (int*)  alloc((size_t)NB * SLACK * sizeof(int));
    int*   csr    = (int*)  alloc((size_t)E * sizeof(int));
    float* g1     = (float*)alloc((size_t)N * HID * sizeof(float));
    float* g2     = (float*)alloc((size_t)N * sizeof(float));
    (void)ws_size; (void)n_in; (void)out_size;

    hipMemsetAsync(bcnt, 0, (size_t)NBMAX * sizeof(int), stream);
    bin_kernel<<<256, 512, 0, stream>>>(ei, E, NB, bcnt, binned);
    sort_kernel<<<NB, 256, 0, stream>>>(binned, bcnt, N, E, off, dinv, csr);
    gemm1_kernel<<<(N + BM - 1) / BM, 256, 0, stream>>>(x, W1, dinv, g1, N);
    gather1_kernel<<<(N + 3) / 4, 256, 0, stream>>>(g1, off, csr, dinv, b1, W2, g2, N);
    gather2_kernel<<<(N + 3) / 4, 256, 0, stream>>>(g2, off, csr, dinv, b2, out, N);
}

// Round 9
// 178.591 us; speedup vs baseline: 3.5373x; 1.0316x over previous
//
#include <hip/hip_runtime.h>
#include <hip/hip_fp16.h>

#define IN_DIM 128
#define HID 64
#define BKT 64            // nodes per bucket
#define NBMAX 1024        // max buckets (N <= 65536)
#define SLACK 2048        // binned capacity per bucket (mean ~1279, >20 sigma)
#define BM 64             // gemm rows per block
#define CHUNKMAX 4096     // bin: max edges cached per block (16 KB LDS)

// Bin edges by 64-node dst bucket, converting from raw (int64|int32) edge_index on the fly.
// int64-detect per-block (reads first 256 int32 words; odd words all zero => int64).
// Entry = (src << 6) | (dst & 63). Per-block LDS histogram -> one global reservation per
// (block,bucket) into zero-initialized bcnt -> direct writes; consecutive slots claimed by
// the same block -> L2 write-combined. Pass 1 caches converted dst in LDS.
__global__ __launch_bounds__(512) void bin_kernel(const void* ei, int E, int NB,
                                                  int* bcnt, int* __restrict__ binned) {
    __shared__ int lhist[NBMAX];
    __shared__ int lbase[NBMAX];
    __shared__ int dcache[CHUNKMAX];
    __shared__ int sflag;
    int t = threadIdx.x;
    if (t < 64) {
        const int* ei32 = (const int*)ei;
        int nz = (ei32[2 * t + 1] != 0) | (ei32[2 * (t + 64) + 1] != 0);
        unsigned long long bl = __ballot(nz);
        if (t == 0) sflag = (bl == 0ULL) ? 1 : 0;
    }
    for (int b = t; b < NBMAX; b += 512) lhist[b] = 0;
    __syncthreads();
    bool w64 = sflag != 0;
    int chunk = (E + gridDim.x - 1) / gridDim.x;
    int cs = blockIdx.x * chunk;
    int ce = cs + chunk; if (ce > E) ce = E;
    for (int i = cs + t; i < ce; i += 512) {
        int d = w64 ? (int)((const long long*)ei)[E + i] : ((const int*)ei)[E + i];
        int j = i - cs;
        if (j < CHUNKMAX) dcache[j] = d;
        atomicAdd(&lhist[d >> 6], 1);
    }
    __syncthreads();
    for (int b = t; b < NB; b += 512) {
        int c = lhist[b];
        if (c) lbase[b] = b * SLACK + atomicAdd(&bcnt[b], c);
        lhist[b] = 0;  // reuse as local cursor
    }
    __syncthreads();
    for (int i = cs + t; i < ce; i += 512) {
        int s = w64 ? (int)((const long long*)ei)[i] : ((const int*)ei)[i];
        int j = i - cs;
        int d = (j < CHUNKMAX) ? dcache[j]
                               : (w64 ? (int)((const long long*)ei)[E + i] : ((const int*)ei)[E + i]);
        int b = d >> 6;
        int p = lbase[b] + atomicAdd(&lhist[b], 1);
        binned[p] = (s << 6) | (d & 63);
    }
}

// Sort within bucket (block-per-bucket). Inline exclusive prefix over bcnt[0..b) (L2-hot).
// LDS 64-counter histogram + wave scan produce exact CSR, off[v], dinv[v]=rsqrt(deg+1).
__global__ __launch_bounds__(256) void sort_kernel(const int* __restrict__ binned,
                                                   const int* __restrict__ bcnt, int N, int E,
                                                   int* __restrict__ off, float* __restrict__ dinv,
                                                   int* __restrict__ csr) {
    __shared__ int hist[BKT];
    __shared__ int cur[BKT];
    __shared__ int pred[4];
    int t = threadIdx.x;
    int b = blockIdx.x;
    int v0 = b * BKT;
    int part = 0;
    for (int j = t; j < b; j += 256) part += bcnt[j];
#pragma unroll
    for (int o = 32; o > 0; o >>= 1) part += __shfl_down(part, o, 64);
    if ((t & 63) == 0) pred[t >> 6] = part;
    if (t < BKT) hist[t] = 0;
    __syncthreads();
    int base = pred[0] + pred[1] + pred[2] + pred[3];
    int cnt_b = bcnt[b];                 // broadcast load
    int si = b * SLACK, ei_ = si + cnt_b;
    for (int i = si + t; i < ei_; i += 256) atomicAdd(&hist[binned[i] & 63], 1);
    __syncthreads();
    if (t < 64) {                        // wave 0: exclusive scan of 64 counters
        int c = hist[t];
        int sc = c;
#pragma unroll
        for (int o = 1; o < 64; o <<= 1) {
            int y = __shfl_up(sc, o, 64);
            if (t >= o) sc += y;
        }
        int start = base + sc - c;
        cur[t] = start;
        int v = v0 + t;
        if (v < N) {
            off[v] = start;
            dinv[v] = rsqrtf((float)(c + 1));
        }
    }
    if (b == 0 && t == 64) off[N] = E;
    __syncthreads();
    for (int i = si + t; i < ei_; i += 256) {
        int a = binned[i];
        int p = atomicAdd(&cur[a & 63], 1);
        csr[p] = a >> 6;
    }
}

// g1 = fp16( dinv ⊙ (x @ W1) ).  W-in-registers: each lane owns W column `lane`
// (128 statically-indexed VGPRs). x rows staged in LDS, read as wave-uniform b128
// broadcasts -> FMA-bound. fp16 store halves gather-phase traffic.
__global__ __launch_bounds__(256) void gemm1_kernel(const float* __restrict__ x, const float* __restrict__ W1,
                                                    const float* __restrict__ dinv, __half* __restrict__ g1, int N) {
    __shared__ float xs[BM * IN_DIM];    // 32 KB = 2048 float4
    int t = threadIdx.x;
    int lane = t & 63, wv = t >> 6;
    int row0 = blockIdx.x * BM;
    float wreg[IN_DIM];
#pragma unroll
    for (int k = 0; k < IN_DIM; ++k) wreg[k] = W1[k * HID + lane];   // coalesced 256B/instr
#pragma unroll
    for (int p = 0; p < 8; ++p) {
        int id = t + 256 * p;            // id = r*32 + g
        int r = id >> 5, g = id & 31;
        float4 v = make_float4(0.f, 0.f, 0.f, 0.f);
        int gr = row0 + r;
        if (gr < N) v = ((const float4*)x)[(size_t)gr * (IN_DIM / 4) + g];
        ((float4*)xs)[id] = v;
    }
    __syncthreads();
    const float4* xs4 = (const float4*)xs;
    for (int rr = 0; rr < 16; ++rr) {
        int r = wv * 16 + rr;
        float acc = 0.f;
#pragma unroll
        for (int k4 = 0; k4 < 32; ++k4) {
            float4 xv = xs4[r * 32 + k4];            // wave-uniform broadcast
            acc = fmaf(xv.x, wreg[4 * k4 + 0], acc);
            acc = fmaf(xv.y, wreg[4 * k4 + 1], acc);
            acc = fmaf(xv.z, wreg[4 * k4 + 2], acc);
            acc = fmaf(xv.w, wreg[4 * k4 + 3], acc);
        }
        int gr = row0 + r;
        if (gr < N) g1[(size_t)gr * HID + lane] = __float2half(dinv[gr] * acc);
    }
}

// Layer-1 aggregation (one wave per node, lane = feature) fused with
// relu + (h1 @ W2) wave-reduction -> g2[v] = dinv[v] * (relu(out1) @ W2)
// fp16 rows: 128B per edge; int4 broadcast index loads; 8 rows in flight.
__global__ __launch_bounds__(256) void gather1_kernel(const __half* __restrict__ g1, const int* __restrict__ off,
                                                      const int* __restrict__ csr, const float* __restrict__ dinv,
                                                      const float* __restrict__ b1, const float* __restrict__ W2,
                                                      float* __restrict__ g2, int N) {
    int wid = threadIdx.x >> 6;
    int lane = threadIdx.x & 63;
    int v = blockIdx.x * 4 + wid;
    if (v >= N) return;
    int s = off[v], e = off[v + 1];
    float acc = __half2float(g1[(size_t)v * HID + lane]);      // self loop
    int i = s;
    while (i < e && (i & 3)) { acc += __half2float(g1[(size_t)csr[i] * HID + lane]); ++i; }
    for (; i + 8 <= e; i += 8) {
        int4 a = *(const int4*)(csr + i);
        int4 b = *(const int4*)(csr + i + 4);
        float f0 = __half2float(g1[(size_t)a.x * HID + lane]);
        float f1 = __half2float(g1[(size_t)a.y * HID + lane]);
        float f2 = __half2float(g1[(size_t)a.z * HID + lane]);
        float f3 = __half2float(g1[(size_t)a.w * HID + lane]);
        float f4 = __half2float(g1[(size_t)b.x * HID + lane]);
        float f5 = __half2float(g1[(size_t)b.y * HID + lane]);
        float f6 = __half2float(g1[(size_t)b.z * HID + lane]);
        float f7 = __half2float(g1[(size_t)b.w * HID + lane]);
        acc += ((f0 + f1) + (f2 + f3)) + ((f4 + f5) + (f6 + f7));
    }
    if (i + 4 <= e) {
        int4 a = *(const int4*)(csr + i);
        float f0 = __half2float(g1[(size_t)a.x * HID + lane]);
        float f1 = __half2float(g1[(size_t)a.y * HID + lane]);
        float f2 = __half2float(g1[(size_t)a.z * HID + lane]);
        float f3 = __half2float(g1[(size_t)a.w * HID + lane]);
        acc += (f0 + f1) + (f2 + f3);
        i += 4;
    }
    for (; i < e; ++i) acc += __half2float(g1[(size_t)csr[i] * HID + lane]);
    float dv = dinv[v];
    float h = fmaxf(fmaf(dv, acc, b1[lane]), 0.0f);   // out1 = dinv*acc + b1, relu
    float p = h * W2[lane];
#pragma unroll
    for (int o = 32; o > 0; o >>= 1) p += __shfl_down(p, o, 64);
    if (lane == 0) g2[v] = dv * p;
}

// Layer-2 aggregation on scalars: out[v] = dinv[v]*(g2[v] + sum g2[u]) + b2
__global__ __launch_bounds__(256) void gather2_kernel(const float* __restrict__ g2, const int* __restrict__ off,
                                                      const int* __restrict__ csr, const float* __restrict__ dinv,
                                                      const float* __restrict__ b2, float* __restrict__ out, int N) {
    int wid = threadIdx.x >> 6;
    int lane = threadIdx.x & 63;
    int v = blockIdx.x * 4 + wid;
    if (v >= N) return;
    int s = off[v], e = off[v + 1];
    float p = 0.f;
    for (int i = s + lane; i < e; i += 64) p += g2[csr[i]];
#pragma unroll
    for (int o = 32; o > 0; o >>= 1) p += __shfl_down(p, o, 64);
    if (lane == 0) out[v] = fmaf(dinv[v], g2[v] + p, b2[0]);
}

extern "C" void kernel_launch(void* const* d_in, const int* in_sizes, int n_in,
                              void* d_out, int out_size, void* d_ws, size_t ws_size,
                              hipStream_t stream) {
    const float* x  = (const float*)d_in[0];
    const void*  ei = d_in[1];
    const float* W1 = (const float*)d_in[2];
    const float* b1 = (const float*)d_in[3];
    const float* W2 = (const float*)d_in[4];
    const float* b2 = (const float*)d_in[5];
    float* out = (float*)d_out;

    int N = in_sizes[0] / IN_DIM;
    int E = in_sizes[1] / 2;
    int NB = (N + BKT - 1) / BKT;   // 782 for N=50000 (<= NBMAX)

    char* w = (char*)d_ws;
    size_t o = 0;
    auto alloc = [&](size_t bytes) { char* p = w + o; o = (o + bytes + 255) & ~(size_t)255; return p; };
    int*    bcnt   = (int*)   alloc((size_t)NBMAX * sizeof(int));
    int*    off    = (int*)   alloc((size_t)(N + 1) * sizeof(int));
    float*  dinv   = (float*) alloc((size_t)N * sizeof(float));
    int*    binned = (int*)   alloc((size_t)NB * SLACK * sizeof(int));
    int*    csr    = (int*)   alloc((size_t)E * sizeof(int));
    __half* g1     = (__half*)alloc((size_t)N * HID * sizeof(__half));
    float*  g2     = (float*) alloc((size_t)N * sizeof(float));
    (void)ws_size; (void)n_in; (void)out_size;

    hipMemsetAsync(bcnt, 0, (size_t)NBMAX * sizeof(int), stream);
    bin_kernel<<<256, 512, 0, stream>>>(ei, E, NB, bcnt, binned);
    sort_kernel<<<NB, 256, 0, stream>>>(binned, bcnt, N, E, off, dinv, csr);
    gemm1_kernel<<<(N + BM - 1) / BM, 256, 0, stream>>>(x, W1, dinv, g1, N);
    gather1_kernel<<<(N + 3) / 4, 256, 0, stream>>>(g1, off, csr, dinv, b1, W2, g2, N);
    gather2_kernel<<<(N + 3) / 4, 256, 0, stream>>>(g2, off, csr, dinv, b2, out, N);
}